// Round 7
// baseline (980.552 us; speedup 1.0000x reference)
//
#include <hip/hip_runtime.h>
#include <hip/hip_bf16.h>

// Problem constants (fixed by setup_inputs)
#define Bn 16
#define Nn 4096
#define Pn 1024
#define Sn 32
#define Cn 64
#define EPSn 1e-5f
#define ALPHAn 0.2f

// Folded weights, OCTET-MAJOR: [oct][K][8] so a wave streams its 8 output
// channels' weights contiguously via s_load (SGPR operands -> zero LDS traffic).
// K dims padded to mult-of-4 with zero rows (67->68, 131->132).
#define W1O 0       // [8][68][8]   = 4352
#define W2O 4352    // [8][64][8]   = 4096
#define W3O 8448    // [16][64][8]  = 8192
#define AO  16640   // [16][132][8] = 16896
#define B1O 33536   // 64
#define B2O 33600   // 64
#define B3O 33664   // 128
#define WSF 33792

__device__ __align__(16) float g_W[WSF];

__global__ void prep_kernel(
    const float* __restrict__ w1, const float* __restrict__ b1,
    const float* __restrict__ g1, const float* __restrict__ bt1,
    const float* __restrict__ m1, const float* __restrict__ v1,
    const float* __restrict__ w2, const float* __restrict__ b2,
    const float* __restrict__ g2, const float* __restrict__ bt2,
    const float* __restrict__ m2, const float* __restrict__ v2,
    const float* __restrict__ w3, const float* __restrict__ b3,
    const float* __restrict__ g3, const float* __restrict__ bt3,
    const float* __restrict__ m3, const float* __restrict__ v3,
    const float* __restrict__ a)
{
  const int idx = blockIdx.x * blockDim.x + threadIdx.x;
  if (idx >= WSF) return;
  float val;
  if (idx < W2O) {                         // W1 octet-major, K pad 68
    int r = idx; const int oct = r / 544; r -= oct * 544;
    const int i = r >> 3, o = oct * 8 + (r & 7);
    const float sc = g1[o] * rsqrtf(v1[o] + EPSn);
    val = (i < 67) ? w1[o * 67 + i] * sc : 0.f;
  } else if (idx < W3O) {                  // W2
    int r = idx - W2O; const int oct = r >> 9; r &= 511;
    const int i = r >> 3, o = oct * 8 + (r & 7);
    val = w2[o * 64 + i] * (g2[o] * rsqrtf(v2[o] + EPSn));
  } else if (idx < AO) {                   // W3
    int r = idx - W3O; const int oct = r >> 9; r &= 511;
    const int i = r >> 3, o = oct * 8 + (r & 7);
    val = w3[o * 64 + i] * (g3[o] * rsqrtf(v3[o] + EPSn));
  } else if (idx < B1O) {                  // A (131x128), K pad 132
    int r = idx - AO; const int oct = r / 1056; r -= oct * 1056;
    const int i = r >> 3, o = oct * 8 + (r & 7);
    val = (i < 131) ? a[i * 128 + o] : 0.f;
  } else if (idx < B2O) {
    const int o = idx - B1O;
    val = (b1[o] - m1[o]) * (g1[o] * rsqrtf(v1[o] + EPSn)) + bt1[o];
  } else if (idx < B3O) {
    const int o = idx - B2O;
    val = (b2[o] - m2[o]) * (g2[o] * rsqrtf(v2[o] + EPSn)) + bt2[o];
  } else {
    const int o = idx - B3O;
    val = (b3[o] - m3[o]) * (g3[o] * rsqrtf(v3[o] + EPSn)) + bt3[o];
  }
  g_W[idx] = val;
}

// LDS (floats). 2 groups per block (wave64 = 2 grp x 32 rows; weights uniform
// per wave). Even row strides (68/132) keep ds_read_b128 16B-aligned; grp
// strides are bank-multiples -> 2-way aliasing only (free, m136).
#define OFF_A    0      // 2*32*68 = 4352 : [rxyz(3)|feat(64)|pad] ; later h2
#define OFF_B    4352   // 4352 : h1
#define OFF_E    0      // 2*4224 = 8448, aliases dead A+B in phase5/6
#define OFF_H3   8704   // 2*32*132 = 8448 : row = [rxyz(3)|h3(128)|pad]
#define OFF_FPS  17152  // 2*68  : [xyz(3)|feat(64)|pad]
#define OFF_F1   17288  // 2*64
#define OFF_F2   17416  // 2*64
#define OFF_F3C  17544  // 2*132 : [new_xyz(3)|F3(128)|pad]
#define OFF_EB   17808  // 2*128
#define SHF      18064  // 72256 B -> 2 blocks/CU

__global__ __launch_bounds__(256) void fused_kernel(
    const float* __restrict__ xyz, const float* __restrict__ points,
    const int* __restrict__ fps_idx, const int* __restrict__ group_idx,
    float* __restrict__ out)
{
  __shared__ __align__(16) float SH[SHF];

  const int t    = threadIdx.x;
  const int lane = t & 63;
  const int grp  = lane >> 5;        // group within block (half-wave)
  const int s    = lane & 31;        // row
  const int wave = __builtin_amdgcn_readfirstlane(t >> 6);
  // t-mapped sections (gather/fps/softmax): 2 groups x 128 threads
  const int tg = t >> 7, tq = t & 127;
  const int gg = blockIdx.x * 2 + tg;
  const int b_t = gg >> 10, p_t = gg & 1023;

  // ---- fps point load ----
  if (tq < 68) {
    float v = 0.f;
    if (tq < 67) {
      const int fi = fps_idx[gg];
      v = (tq < 3) ? xyz[b_t * 3 * Nn + tq * Nn + fi]
                   : points[b_t * Cn * Nn + (tq - 3) * Nn + fi];
    }
    SH[OFF_FPS + tg * 68 + tq] = v;
  }
  __syncthreads();

  // ---- gather neighbors: 128 thr/grp = 32 rows x 4 ch-groups ----
  {
    const int s0 = tq >> 2, cg = tq & 3;
    const int gi = group_idx[gg * Sn + s0];
    const float* prow = points + b_t * Cn * Nn + gi;
    float* arow = SH + OFF_A + tg * 2176 + s0 * 68;
    const int c0 = cg * 16;
    #pragma unroll
    for (int k = 0; k < 16; ++k) arow[3 + c0 + k] = prow[(c0 + k) * Nn];
    if (cg == 0) {
      float* hrow = SH + OFF_H3 + tg * 4224 + s0 * 132;
      #pragma unroll
      for (int d = 0; d < 3; ++d) {
        const float r = xyz[b_t * 3 * Nn + d * Nn + gi] - SH[OFF_FPS + tg * 68 + d];
        arow[d] = r;
        hrow[d] = r;
      }
      arow[67] = 0.f;
      hrow[131] = 0.f;
    }
  }
  __syncthreads();

  const float* inA  = SH + OFF_A  + grp * 2176 + s * 68;
  float*       rowB = SH + OFF_B  + grp * 2176 + s * 68;
  const float* inH  = SH + OFF_H3 + grp * 4224 + s * 132;

  // ===== Phase 1: 67->64 (K=68 padded). Wave covers octets {wave, wave+4} =====
  #pragma unroll
  for (int pass = 0; pass < 2; ++pass) {
    const int oct = wave + 4 * pass;
    const int wof = __builtin_amdgcn_readfirstlane(W1O + oct * 544);
    const int bof = __builtin_amdgcn_readfirstlane(B1O + oct * 8);
    float acc[8];
    #pragma unroll
    for (int j = 0; j < 8; ++j) acc[j] = g_W[bof + j];
    #pragma unroll 4
    for (int i4 = 0; i4 < 68; i4 += 4) {
      const float4 v4 = *(const float4*)(inA + i4);
      const float* wp = g_W + wof + i4 * 8;   // uniform -> s_load
      #pragma unroll
      for (int j = 0; j < 8; ++j) acc[j] = fmaf(v4.x, wp[j], acc[j]);
      #pragma unroll
      for (int j = 0; j < 8; ++j) acc[j] = fmaf(v4.y, wp[8 + j], acc[j]);
      #pragma unroll
      for (int j = 0; j < 8; ++j) acc[j] = fmaf(v4.z, wp[16 + j], acc[j]);
      #pragma unroll
      for (int j = 0; j < 8; ++j) acc[j] = fmaf(v4.w, wp[24 + j], acc[j]);
    }
    float4 r0, r1;
    r0.x = fmaxf(acc[0], 0.f); r0.y = fmaxf(acc[1], 0.f);
    r0.z = fmaxf(acc[2], 0.f); r0.w = fmaxf(acc[3], 0.f);
    r1.x = fmaxf(acc[4], 0.f); r1.y = fmaxf(acc[5], 0.f);
    r1.z = fmaxf(acc[6], 0.f); r1.w = fmaxf(acc[7], 0.f);
    *(float4*)(rowB + oct * 8)     = r0;
    *(float4*)(rowB + oct * 8 + 4) = r1;
  }
  // fps row, layer1: 64 outs/grp, K split 2 (34+34 over padded 68)
  {
    const int o = tq >> 1, kh = tq & 1;
    const float* wp = g_W + W1O + (o >> 3) * 544 + (o & 7);
    const float* f = SH + OFF_FPS + tg * 68;
    float a = 0.f;
    #pragma unroll 4
    for (int i = kh * 34; i < kh * 34 + 34; ++i) a = fmaf(f[i], wp[i * 8], a);
    a += __shfl_xor(a, 1);
    if (kh == 0) SH[OFF_F1 + tg * 64 + o] = fmaxf(a + g_W[B1O + o], 0.f);
  }
  __syncthreads();

  // ===== Phase 2: 64->64. Reads h1 (B), writes h2 into A region =====
  #pragma unroll
  for (int pass = 0; pass < 2; ++pass) {
    const int oct = wave + 4 * pass;
    const int wof = __builtin_amdgcn_readfirstlane(W2O + oct * 512);
    const int bof = __builtin_amdgcn_readfirstlane(B2O + oct * 8);
    float acc[8];
    #pragma unroll
    for (int j = 0; j < 8; ++j) acc[j] = g_W[bof + j];
    #pragma unroll 4
    for (int i4 = 0; i4 < 64; i4 += 4) {
      const float4 v4 = *(const float4*)(rowB + i4);
      const float* wp = g_W + wof + i4 * 8;
      #pragma unroll
      for (int j = 0; j < 8; ++j) acc[j] = fmaf(v4.x, wp[j], acc[j]);
      #pragma unroll
      for (int j = 0; j < 8; ++j) acc[j] = fmaf(v4.y, wp[8 + j], acc[j]);
      #pragma unroll
      for (int j = 0; j < 8; ++j) acc[j] = fmaf(v4.z, wp[16 + j], acc[j]);
      #pragma unroll
      for (int j = 0; j < 8; ++j) acc[j] = fmaf(v4.w, wp[24 + j], acc[j]);
    }
    float4 r0, r1;
    r0.x = fmaxf(acc[0], 0.f); r0.y = fmaxf(acc[1], 0.f);
    r0.z = fmaxf(acc[2], 0.f); r0.w = fmaxf(acc[3], 0.f);
    r1.x = fmaxf(acc[4], 0.f); r1.y = fmaxf(acc[5], 0.f);
    r1.z = fmaxf(acc[6], 0.f); r1.w = fmaxf(acc[7], 0.f);
    *(float4*)((float*)(SH + OFF_A + grp * 2176 + s * 68) + oct * 8)     = r0;
    *(float4*)((float*)(SH + OFF_A + grp * 2176 + s * 68) + oct * 8 + 4) = r1;
  }
  // fps row, layer2
  {
    const int o = tq >> 1, kh = tq & 1;
    const float* wp = g_W + W2O + (o >> 3) * 512 + (o & 7);
    const float* f = SH + OFF_F1 + tg * 64;
    float a = 0.f;
    #pragma unroll 4
    for (int i = kh * 32; i < kh * 32 + 32; ++i) a = fmaf(f[i], wp[i * 8], a);
    a += __shfl_xor(a, 1);
    if (kh == 0) SH[OFF_F2 + tg * 64 + o] = fmaxf(a + g_W[B2O + o], 0.f);
  }
  __syncthreads();

  // ===== Phase 3: 64->128 (16 octets -> 4 passes). Writes h3 into H3 rows =====
  #pragma unroll
  for (int pass = 0; pass < 4; ++pass) {
    const int oct = wave + 4 * pass;
    const int wof = __builtin_amdgcn_readfirstlane(W3O + oct * 512);
    const int bof = __builtin_amdgcn_readfirstlane(B3O + oct * 8);
    float acc[8];
    #pragma unroll
    for (int j = 0; j < 8; ++j) acc[j] = g_W[bof + j];
    #pragma unroll 4
    for (int i4 = 0; i4 < 64; i4 += 4) {
      const float4 v4 = *(const float4*)(inA + i4);   // h2
      const float* wp = g_W + wof + i4 * 8;
      #pragma unroll
      for (int j = 0; j < 8; ++j) acc[j] = fmaf(v4.x, wp[j], acc[j]);
      #pragma unroll
      for (int j = 0; j < 8; ++j) acc[j] = fmaf(v4.y, wp[8 + j], acc[j]);
      #pragma unroll
      for (int j = 0; j < 8; ++j) acc[j] = fmaf(v4.z, wp[16 + j], acc[j]);
      #pragma unroll
      for (int j = 0; j < 8; ++j) acc[j] = fmaf(v4.w, wp[24 + j], acc[j]);
    }
    float* hrow = SH + OFF_H3 + grp * 4224 + s * 132 + 3 + oct * 8;
    #pragma unroll
    for (int j = 0; j < 8; ++j) hrow[j] = fmaxf(acc[j], 0.f);
  }
  // fps row, layer3: 128 outs/grp, full K=64
  {
    const int o = tq;
    const float* wp = g_W + W3O + (o >> 3) * 512 + (o & 7);
    const float* f = SH + OFF_F2 + tg * 64;
    float a = 0.f;
    #pragma unroll 4
    for (int i = 0; i < 64; ++i) a = fmaf(f[i], wp[i * 8], a);
    float* f3c = SH + OFF_F3C + tg * 132;
    f3c[3 + o] = fmaxf(a + g_W[B3O + o], 0.f);
    if (o < 3) f3c[o] = SH[OFF_FPS + tg * 68 + o];
    if (o == 0) f3c[131] = 0.f;
  }
  __syncthreads();

  // ===== ebias: [new_xyz|F3](131) . a -> 128 per grp =====
  {
    const int o = tq;
    const float* wp = g_W + AO + (o >> 3) * 1056 + (o & 7);
    const float* f = SH + OFF_F3C + tg * 132;
    float a = 0.f;
    #pragma unroll 4
    for (int i = 0; i < 132; ++i) a = fmaf(f[i], wp[i * 8], a);
    SH[OFF_EB + tg * 128 + o] = a;
  }
  __syncthreads();   // sEb ready; sA/sB dead -> sE region writable

  // ===== Phase 5: e = leaky(eb - [rxyz|h3].a), 16 octets -> 4 passes =====
  #pragma unroll
  for (int pass = 0; pass < 4; ++pass) {
    const int oct = wave + 4 * pass;
    const int wof = __builtin_amdgcn_readfirstlane(AO + oct * 1056);
    float acc[8];
    #pragma unroll
    for (int j = 0; j < 8; ++j) acc[j] = 0.f;
    #pragma unroll 4
    for (int i4 = 0; i4 < 132; i4 += 4) {
      const float4 v4 = *(const float4*)(inH + i4);
      const float* wp = g_W + wof + i4 * 8;
      #pragma unroll
      for (int j = 0; j < 8; ++j) acc[j] = fmaf(v4.x, wp[j], acc[j]);
      #pragma unroll
      for (int j = 0; j < 8; ++j) acc[j] = fmaf(v4.y, wp[8 + j], acc[j]);
      #pragma unroll
      for (int j = 0; j < 8; ++j) acc[j] = fmaf(v4.z, wp[16 + j], acc[j]);
      #pragma unroll
      for (int j = 0; j < 8; ++j) acc[j] = fmaf(v4.w, wp[24 + j], acc[j]);
    }
    const float* ebp = SH + OFF_EB + grp * 128 + oct * 8;
    float4 r0, r1;
    float e;
    e = ebp[0] - acc[0]; r0.x = (e > 0.f) ? e : ALPHAn * e;
    e = ebp[1] - acc[1]; r0.y = (e > 0.f) ? e : ALPHAn * e;
    e = ebp[2] - acc[2]; r0.z = (e > 0.f) ? e : ALPHAn * e;
    e = ebp[3] - acc[3]; r0.w = (e > 0.f) ? e : ALPHAn * e;
    e = ebp[4] - acc[4]; r1.x = (e > 0.f) ? e : ALPHAn * e;
    e = ebp[5] - acc[5]; r1.y = (e > 0.f) ? e : ALPHAn * e;
    e = ebp[6] - acc[6]; r1.z = (e > 0.f) ? e : ALPHAn * e;
    e = ebp[7] - acc[7]; r1.w = (e > 0.f) ? e : ALPHAn * e;
    float* erow = SH + OFF_E + grp * 4224 + s * 132 + oct * 8;
    *(float4*)(erow)     = r0;
    *(float4*)(erow + 4) = r1;
  }
  __syncthreads();

  // ===== softmax over s + pooled sum; outputs =====
  {
    const int j = tq;
    const float* ecol = SH + OFF_E + tg * 4224 + j;
    const float* hcol = SH + OFF_H3 + tg * 4224 + 3 + j;
    float mx = -3.4e38f;
    #pragma unroll 4
    for (int si = 0; si < 32; ++si) mx = fmaxf(mx, ecol[si * 132]);
    float den = 0.f, pool = 0.f;
    #pragma unroll 4
    for (int si = 0; si < 32; ++si) {
      const float w = __expf(ecol[si * 132] - mx);
      den += w;
      pool = fmaf(w, hcol[si * 132], pool);
    }
    out[Bn * 3 * Pn + (b_t * 128 + j) * Pn + p_t] = pool / den;
    if (j < 3) out[(b_t * 3 + j) * Pn + p_t] = SH[OFF_FPS + tg * 68 + j];
  }
}

extern "C" void kernel_launch(void* const* d_in, const int* in_sizes, int n_in,
                              void* d_out, int out_size, void* d_ws, size_t ws_size,
                              hipStream_t stream) {
  const float* xyz       = (const float*)d_in[0];
  const float* points    = (const float*)d_in[1];
  const int*   fps_idx   = (const int*)d_in[2];
  const int*   group_idx = (const int*)d_in[3];

  prep_kernel<<<(WSF + 255) / 256, 256, 0, stream>>>(
      (const float*)d_in[4],  (const float*)d_in[5],
      (const float*)d_in[6],  (const float*)d_in[7],
      (const float*)d_in[8],  (const float*)d_in[9],
      (const float*)d_in[10], (const float*)d_in[11],
      (const float*)d_in[12], (const float*)d_in[13],
      (const float*)d_in[14], (const float*)d_in[15],
      (const float*)d_in[16], (const float*)d_in[17],
      (const float*)d_in[18], (const float*)d_in[19],
      (const float*)d_in[20], (const float*)d_in[21],
      (const float*)d_in[22]);

  fused_kernel<<<Bn * Pn / 2, 256, 0, stream>>>(xyz, points, fps_idx, group_idx,
                                                (float*)d_out);
}